// Round 18
// baseline (431.484 us; speedup 1.0000x reference)
//
#include <hip/hip_runtime.h>
#include <math.h>

#define BB 16
#define SS 8192
#define HH 768
#define NH 12
#define HD 64
#define SCALE 0.125f
#define CPB 64            // 1024 blocks = 4/CU exactly; 128 rows/chunk = 32 uniform 4-row tiles

// ws float offsets
#define WS_QKP   0        // 9216
#define WS_C     9216     // 16
#define WS_GATE  9232     // 768
#define WS_OP    10240    // 16*768
#define WS_POOLED 22528   // 16*12*768
#define WS_STATS 169984   // pm[BB*CPB*NH], pl[BB*CPB*NH], part[BB*CPB*NH*HH] (~38.5 MB)

// async global->LDS, 16B per lane; global addr per-lane, lds dest wave-uniform
#define GLL(g, l) __builtin_amdgcn_global_load_lds(                      \
    (const __attribute__((address_space(1))) void*)(g),                  \
    (__attribute__((address_space(3))) void*)(l), 16, 0, 0)

__device__ __forceinline__ float dot4(float4 a, float4 b) {
    return a.x * b.x + a.y * b.y + a.z * b.z + a.w * b.w;
}

// DPP rotate-add within 16-lane rows (VALU pipe)
template<int CTRL>
__device__ __forceinline__ float dpp_add(float x) {
    int r = __builtin_amdgcn_update_dpp(0, __float_as_int(x), CTRL, 0xF, 0xF, true);
    return x + __int_as_float(r);
}

// all-lane sum across 64 lanes: 4 DPP (16-group) + 2 shfl_xor (R12-proven path)
__device__ __forceinline__ float sum64_all(float x) {
    x = dpp_add<0x121>(x);   // row_ror:1
    x = dpp_add<0x122>(x);   // row_ror:2
    x = dpp_add<0x124>(x);   // row_ror:4
    x = dpp_add<0x128>(x);   // row_ror:8  -> every lane = its 16-group sum
    x += __shfl_xor(x, 16, 64);
    x += __shfl_xor(x, 32, 64);
    return x;                // full 64-lane sum, all lanes
}

// ---------------- K0: qkp = scale*Wk^T q (+c), gate ----------------
__global__ __launch_bounds__(256) void k_pre(const float* __restrict__ query,
                                             const float* __restrict__ w_kv,
                                             const float* __restrict__ b_kv,
                                             const float* __restrict__ w_gate,
                                             const float* __restrict__ b_gate,
                                             float* __restrict__ ws) {
    int blk = blockIdx.x, t = threadIdx.x;
    if (blk < 36) {
        int h = blk / 3;
        int j = (blk % 3) * 256 + t;
        float acc = 0.f;
        #pragma unroll 8
        for (int d = 0; d < HD; d++)
            acc += query[h * HD + d] * w_kv[(size_t)(h * HD + d) * HH + j];
        ws[WS_QKP + h * HH + j] = acc * SCALE;
    } else if (blk == 36) {
        if (t < NH) {
            float acc = 0.f;
            for (int d = 0; d < HD; d++)
                acc += query[t * HD + d] * b_kv[t * HD + d];
            ws[WS_C + t] = acc * SCALE;
        }
    } else {
        // gate: 96 blocks, 8 rows each (2 per wave)
        __shared__ __align__(16) float qs[HH];
        for (int i = t; i < HH; i += 256) qs[i] = query[i];
        __syncthreads();
        int base = (blk - 37) * 8;
        int wave = t >> 6, lane = t & 63;
        #pragma unroll
        for (int o = 0; o < 2; o++) {
            int i = base + wave * 2 + o;
            const float* wr = w_gate + (size_t)i * HH + lane * 4;
            float s = 0.f;
            #pragma unroll
            for (int kk = 0; kk < 3; kk++) {
                float4 wv = *(const float4*)(wr + 256 * kk);
                float4 qv = *(const float4*)&qs[lane * 4 + 256 * kk];
                s += dot4(wv, qv);
            }
            #pragma unroll
            for (int off = 1; off < 64; off <<= 1) s += __shfl_xor(s, off, 64);
            if (lane == 0) {
                float z = s + b_gate[i];
                ws[WS_GATE + i] = 1.0f / (1.0f + expf(-z));
            }
        }
    }
}

// ---------------- K1: fused scores + online softmax + pool ----------------
// R17 compute body (bit-identical numerics); 4-row double-buffered tiles via
// global_load_lds (wave w stages row w); 4 blocks/CU (16 waves) at (256,4).
__global__ __launch_bounds__(256, 4) void k_fused(const float* __restrict__ x,
                                                  const float* __restrict__ ws,
                                                  float* __restrict__ part,
                                                  float* __restrict__ pm,
                                                  float* __restrict__ pl) {
    __shared__ __align__(16) float xt[2][4 * HH];     // 24.6 KB

    int t = threadIdx.x;
    int cblk = blockIdx.x, b = blockIdx.y;
    int wave = t >> 6, lane = t & 63;

    // qkp for this wave's 3 heads at this lane's fixed col slice -> registers
    float4 qr[3][3];
    #pragma unroll
    for (int j = 0; j < 3; j++)
        #pragma unroll
        for (int c2 = 0; c2 < 3; c2++)
            qr[j][c2] = *(const float4*)(ws + WS_QKP + (3 * wave + j) * HH + 4 * lane + 256 * c2);
    float cr[3];
    #pragma unroll
    for (int j = 0; j < 3; j++) cr[j] = ws[WS_C + 3 * wave + j];

    float P[3][12];
    #pragma unroll
    for (int j = 0; j < 3; j++)
        #pragma unroll
        for (int cc = 0; cc < 12; cc++) P[j][cc] = 0.f;
    float m[3] = { -1e30f, -1e30f, -1e30f };
    float l[3] = { 0.f, 0.f, 0.f };

    const float* xb = x + ((size_t)b * SS + (size_t)cblk * 128) * HH;

    // prologue: stage tile 0 -> buf 0 (wave w stages row w)
    {
        const float* g = xb + (size_t)wave * HH + 4 * lane;
        float* l0 = &xt[0][wave * HH];
        GLL(g, l0); GLL(g + 256, l0 + 256); GLL(g + 512, l0 + 512);
    }
    __syncthreads();

    for (int tile = 0; tile < 32; tile++) {
        int cur = tile & 1;
        if (tile + 1 < 32) {
            const float* g = xb + ((size_t)(tile + 1) * 4 + wave) * HH + 4 * lane;
            float* ld = &xt[cur ^ 1][wave * HH];
            GLL(g, ld); GLL(g + 256, ld + 256); GLL(g + 512, ld + 512);
        }
        const float* xc = xt[cur];

        // two 2-row chunks: identical compute/order to R12/R17
        #pragma unroll
        for (int ch = 0; ch < 2; ch++) {
            const float* xr = xc + (2 * ch) * HH;
            float4 xv[2][3];
            #pragma unroll
            for (int r = 0; r < 2; r++) {
                xv[r][0] = *(const float4*)&xr[r * HH + 4 * lane];
                xv[r][1] = *(const float4*)&xr[r * HH + 4 * lane + 256];
                xv[r][2] = *(const float4*)&xr[r * HH + 4 * lane + 512];
            }

            float s[2][3];
            #pragma unroll
            for (int r = 0; r < 2; r++)
                #pragma unroll
                for (int j = 0; j < 3; j++) {
                    float a = dot4(xv[r][0], qr[j][0]) + dot4(xv[r][1], qr[j][1])
                            + dot4(xv[r][2], qr[j][2]);
                    s[r][j] = sum64_all(a) + cr[j];
                }

            // online softmax + pool; rescale only when the max grows (uniform branch)
            #pragma unroll
            for (int j = 0; j < 3; j++) {
                float tm = fmaxf(s[0][j], s[1][j]);
                if (tm > m[j]) {
                    float f = __expf(m[j] - tm);
                    m[j] = tm;
                    l[j] *= f;
                    #pragma unroll
                    for (int cc = 0; cc < 12; cc++) P[j][cc] *= f;
                }
                float w0 = __expf(s[0][j] - m[j]);
                float w1 = __expf(s[1][j] - m[j]);
                l[j] += w0 + w1;
                #pragma unroll
                for (int k = 0; k < 3; k++) {
                    P[j][4*k+0] += w0 * xv[0][k].x + w1 * xv[1][k].x;
                    P[j][4*k+1] += w0 * xv[0][k].y + w1 * xv[1][k].y;
                    P[j][4*k+2] += w0 * xv[0][k].z + w1 * xv[1][k].z;
                    P[j][4*k+3] += w0 * xv[0][k].w + w1 * xv[1][k].w;
                }
            }
        }

        __syncthreads();   // staged tile landed; cur free for next stage
    }

    // write partials: head 3w+j, cols 4*lane + 256*k (+0..3)
    size_t blkc = (size_t)b * CPB + cblk;
    #pragma unroll
    for (int j = 0; j < 3; j++) {
        #pragma unroll
        for (int k = 0; k < 3; k++) {
            float4 v = make_float4(P[j][4*k+0], P[j][4*k+1], P[j][4*k+2], P[j][4*k+3]);
            *(float4*)&part[(blkc * NH + 3 * wave + j) * HH + 256 * k + 4 * lane] = v;
        }
        if (lane == 0) {
            pm[blkc * NH + 3 * wave + j] = m[j];
            pl[blkc * NH + 3 * wave + j] = l[j];
        }
    }
}

// ---------------- K2: combine chunk partials -> pooled ----------------
__global__ __launch_bounds__(256) void k_comb(const float* __restrict__ part,
                                              const float* __restrict__ pm,
                                              const float* __restrict__ pl,
                                              float* __restrict__ pooled) {
    int h = blockIdx.x, b = blockIdx.y, t = threadIdx.x;
    __shared__ float fac[64];
    __shared__ float Ish;
    float mval = -1e30f, lval = 0.f;
    if (t < CPB) {
        mval = pm[((size_t)b * CPB + t) * NH + h];
        lval = pl[((size_t)b * CPB + t) * NH + h];
    }
    if (t < 64) {
        float m = mval;
        #pragma unroll
        for (int off = 1; off < 64; off <<= 1) m = fmaxf(m, __shfl_xor(m, off, 64));
        float fc = (t < CPB) ? __expf(mval - m) : 0.f;
        fac[t] = fc;
        float l = lval * fc;
        #pragma unroll
        for (int off = 1; off < 64; off <<= 1) l += __shfl_xor(l, off, 64);
        if (t == 0) Ish = 1.0f / l;
    }
    __syncthreads();
    float inv = Ish;
    #pragma unroll
    for (int kk = 0; kk < 3; kk++) {
        int col = kk * 256 + t;
        float s = 0.f;
        #pragma unroll 8
        for (int c = 0; c < CPB; c++)
            s += part[(((size_t)b * CPB + c) * NH + h) * HH + col] * fac[c];
        pooled[((size_t)b * NH + h) * HH + col] = s * inv;
    }
}

// ---------------- K3: op = W_v pooled + b_v  (grid 24 x BB, 8 outputs/wave) ----------------
__global__ __launch_bounds__(256) void k_v(const float* __restrict__ pooled,
                                           const float* __restrict__ w_kv,
                                           const float* __restrict__ b_kv,
                                           float* __restrict__ op) {
    int seg = blockIdx.x, b = blockIdx.y, t = threadIdx.x;
    __shared__ __align__(16) float pv[HH];
    int head = seg >> 1;
    for (int i = t; i < HH; i += 256)
        pv[i] = pooled[((size_t)b * NH + head) * HH + i];
    __syncthreads();
    int wave = t >> 6, lane = t & 63;
    #pragma unroll
    for (int o = 0; o < 8; o++) {
        int hd = seg * 32 + wave * 8 + o;
        const float* wr = w_kv + (size_t)(HH + hd) * HH + lane * 4;
        float s = 0.f;
        #pragma unroll
        for (int kk = 0; kk < 3; kk++) {
            float4 wv = *(const float4*)(wr + 256 * kk);
            float4 qv = *(const float4*)&pv[lane * 4 + 256 * kk];
            s += dot4(wv, qv);
        }
        #pragma unroll
        for (int off = 1; off < 64; off <<= 1) s += __shfl_xor(s, off, 64);
        if (lane == 0) op[(size_t)b * HH + hd] = s + b_kv[HH + hd];
    }
}

// ---------------- K4: out = gate * (W_out op + b_out)  (grid 24 x BB) ----------------
__global__ __launch_bounds__(256) void k_fin(const float* __restrict__ op_in,
                                             const float* __restrict__ w_out,
                                             const float* __restrict__ b_out,
                                             const float* __restrict__ gate,
                                             float* __restrict__ out) {
    int seg = blockIdx.x, b = blockIdx.y, t = threadIdx.x;
    __shared__ __align__(16) float ov[HH];
    for (int i = t; i < HH; i += 256) ov[i] = op_in[(size_t)b * HH + i];
    __syncthreads();
    int wave = t >> 6, lane = t & 63;
    #pragma unroll
    for (int o = 0; o < 8; o++) {
        int i = seg * 32 + wave * 8 + o;
        const float* wr = w_out + (size_t)i * HH + lane * 4;
        float s = 0.f;
        #pragma unroll
        for (int kk = 0; kk < 3; kk++) {
            float4 wv = *(const float4*)(wr + 256 * kk);
            float4 qv = *(const float4*)&ov[lane * 4 + 256 * kk];
            s += dot4(wv, qv);
        }
        #pragma unroll
        for (int off = 1; off < 64; off <<= 1) s += __shfl_xor(s, off, 64);
        if (lane == 0) out[(size_t)b * HH + i] = gate[i] * (s + b_out[i]);
    }
}

extern "C" void kernel_launch(void* const* d_in, const int* in_sizes, int n_in,
                              void* d_out, int out_size, void* d_ws, size_t ws_size,
                              hipStream_t stream) {
    const float* x      = (const float*)d_in[0];
    const float* query  = (const float*)d_in[1];
    const float* w_kv   = (const float*)d_in[2];
    const float* b_kv   = (const float*)d_in[3];
    const float* w_out  = (const float*)d_in[4];
    const float* b_out  = (const float*)d_in[5];
    const float* w_gate = (const float*)d_in[6];
    const float* b_gate = (const float*)d_in[7];
    float* ws  = (float*)d_ws;
    float* out = (float*)d_out;

    float* gate   = ws + WS_GATE;
    float* opbuf  = ws + WS_OP;
    float* pooled = ws + WS_POOLED;
    float* pm     = ws + WS_STATS;
    float* pl     = pm + (size_t)BB * CPB * NH;
    float* part   = pl + (size_t)BB * CPB * NH;

    k_pre<<<133, 256, 0, stream>>>(query, w_kv, b_kv, w_gate, b_gate, ws);
    k_fused<<<dim3(CPB, BB), 256, 0, stream>>>(x, ws, part, pm, pl);
    k_comb<<<dim3(NH, BB), 256, 0, stream>>>(part, pm, pl, pooled);
    k_v<<<dim3(24, BB), 256, 0, stream>>>(pooled, w_kv, b_kv, opbuf);
    k_fin<<<dim3(24, BB), 256, 0, stream>>>(opbuf, w_out, b_out, gate, out);
}

// Round 19
// 175.416 us; speedup vs baseline: 2.4598x; 2.4598x over previous
//
#include <hip/hip_runtime.h>
#include <math.h>

#define BB 16
#define SS 8192
#define HH 768
#define NH 12
#define HD 64
#define SCALE 0.125f
#define CPB 48            // 768 blocks = 3/CU; 32 chunks x 176 rows + 16 x 160 rows (8-row tiles)

// ws float offsets
#define WS_QKP   0        // 9216
#define WS_C     9216     // 16
#define WS_GATE  9232     // 768
#define WS_OP    10240    // 16*768
#define WS_POOLED 22528   // 16*12*768 (unused by fused tail, kept for layout stability)
#define WS_STATS 169984   // pm[BB*CPB*NH], pl[BB*CPB*NH], part[BB*CPB*NH*HH]

// async global->LDS, 16B per lane; global addr per-lane, lds dest wave-uniform
#define GLL(g, l) __builtin_amdgcn_global_load_lds(                      \
    (const __attribute__((address_space(1))) void*)(g),                  \
    (__attribute__((address_space(3))) void*)(l), 16, 0, 0)

__device__ __forceinline__ float dot4(float4 a, float4 b) {
    return a.x * b.x + a.y * b.y + a.z * b.z + a.w * b.w;
}

// DPP add (VALU pipe)
template<int CTRL>
__device__ __forceinline__ float dpp_add(float x) {
    int r = __builtin_amdgcn_update_dpp(0, __float_as_int(x), CTRL, 0xF, 0xF, true);
    return x + __int_as_float(r);
}

// full 64-lane sum entirely on VALU (R14-numerics-proven): 4x row_ror +
// row_bcast15 + row_bcast31 -> lane 63 holds total; readlane broadcasts.
// Zero DS-pipe ops; result wave-uniform.
__device__ __forceinline__ float sum64_u(float x) {
    x = dpp_add<0x121>(x);   // row_ror:1
    x = dpp_add<0x122>(x);   // row_ror:2
    x = dpp_add<0x124>(x);   // row_ror:4
    x = dpp_add<0x128>(x);   // row_ror:8
    x = dpp_add<0x142>(x);   // row_bcast:15
    x = dpp_add<0x143>(x);   // row_bcast:31
    return __int_as_float(__builtin_amdgcn_readlane(__float_as_int(x), 63));
}

// ---------------- K0: qkp = scale*Wk^T q (+c), gate ----------------
__global__ __launch_bounds__(256) void k_pre(const float* __restrict__ query,
                                             const float* __restrict__ w_kv,
                                             const float* __restrict__ b_kv,
                                             const float* __restrict__ w_gate,
                                             const float* __restrict__ b_gate,
                                             float* __restrict__ ws) {
    int blk = blockIdx.x, t = threadIdx.x;
    if (blk < 36) {
        int h = blk / 3;
        int j = (blk % 3) * 256 + t;
        float acc = 0.f;
        #pragma unroll 8
        for (int d = 0; d < HD; d++)
            acc += query[h * HD + d] * w_kv[(size_t)(h * HD + d) * HH + j];
        ws[WS_QKP + h * HH + j] = acc * SCALE;
    } else if (blk == 36) {
        if (t < NH) {
            float acc = 0.f;
            for (int d = 0; d < HD; d++)
                acc += query[t * HD + d] * b_kv[t * HD + d];
            ws[WS_C + t] = acc * SCALE;
        }
    } else {
        // gate: 96 blocks, 8 rows each (2 per wave)
        __shared__ __align__(16) float qs[HH];
        for (int i = t; i < HH; i += 256) qs[i] = query[i];
        __syncthreads();
        int base = (blk - 37) * 8;
        int wave = t >> 6, lane = t & 63;
        #pragma unroll
        for (int o = 0; o < 2; o++) {
            int i = base + wave * 2 + o;
            const float* wr = w_gate + (size_t)i * HH + lane * 4;
            float s = 0.f;
            #pragma unroll
            for (int kk = 0; kk < 3; kk++) {
                float4 wv = *(const float4*)(wr + 256 * kk);
                float4 qv = *(const float4*)&qs[lane * 4 + 256 * kk];
                s += dot4(wv, qv);
            }
            #pragma unroll
            for (int off = 1; off < 64; off <<= 1) s += __shfl_xor(s, off, 64);
            if (lane == 0) {
                float z = s + b_gate[i];
                ws[WS_GATE + i] = 1.0f / (1.0f + expf(-z));
            }
        }
    }
}

// ---------------- K1: fused scores + online softmax + pool ----------------
// R17 structure frozen ((256,3), 8-row dbuf tiles, 2-row chunks); single swap:
// score reduce = sum64_u (all-VALU DPP, no ds_bpermute). Scores wave-uniform.
__global__ __launch_bounds__(256, 3) void k_fused(const float* __restrict__ x,
                                                  const float* __restrict__ ws,
                                                  float* __restrict__ part,
                                                  float* __restrict__ pm,
                                                  float* __restrict__ pl) {
    __shared__ __align__(16) float xt[2][8 * HH];     // 48 KB

    int t = threadIdx.x;
    int cblk = blockIdx.x, b = blockIdx.y;
    int wave = t >> 6, lane = t & 63;

    // qkp for this wave's 3 heads at this lane's fixed col slice -> registers
    float4 qr[3][3];
    #pragma unroll
    for (int j = 0; j < 3; j++)
        #pragma unroll
        for (int c2 = 0; c2 < 3; c2++)
            qr[j][c2] = *(const float4*)(ws + WS_QKP + (3 * wave + j) * HH + 4 * lane + 256 * c2);
    float cr[3];
    #pragma unroll
    for (int j = 0; j < 3; j++) cr[j] = ws[WS_C + 3 * wave + j];

    float P[3][12];
    #pragma unroll
    for (int j = 0; j < 3; j++)
        #pragma unroll
        for (int cc = 0; cc < 12; cc++) P[j][cc] = 0.f;
    float m[3] = { -1e30f, -1e30f, -1e30f };
    float l[3] = { 0.f, 0.f, 0.f };

    int nt    = (cblk < 32) ? 22 : 20;                 // 8-row tiles
    int rows0 = (cblk < 32) ? cblk * 176 : 5632 + (cblk - 32) * 160;
    const float* xb = x + ((size_t)b * SS + rows0) * HH;

    // prologue: stage tile 0 -> buf 0 (wave w stages rows 2w, 2w+1)
    {
        const float* g = xb + (size_t)(2 * wave) * HH + 4 * lane;
        float* l0 = &xt[0][(2 * wave) * HH];
        GLL(g, l0);           GLL(g + 256, l0 + 256);           GLL(g + 512, l0 + 512);
        GLL(g + HH, l0 + HH); GLL(g + HH + 256, l0 + HH + 256); GLL(g + HH + 512, l0 + HH + 512);
    }
    __syncthreads();

    for (int tile = 0; tile < nt; tile++) {
        int cur = tile & 1;
        if (tile + 1 < nt) {
            const float* g = xb + ((size_t)(tile + 1) * 8 + 2 * wave) * HH + 4 * lane;
            float* ld = &xt[cur ^ 1][(2 * wave) * HH];
            GLL(g, ld);           GLL(g + 256, ld + 256);           GLL(g + 512, ld + 512);
            GLL(g + HH, ld + HH); GLL(g + HH + 256, ld + HH + 256); GLL(g + HH + 512, ld + HH + 512);
        }
        const float* xc = xt[cur];

        // four 2-row chunks
        #pragma unroll
        for (int ch = 0; ch < 4; ch++) {
            const float* xr = xc + (2 * ch) * HH;
            float4 xv[2][3];
            #pragma unroll
            for (int r = 0; r < 2; r++) {
                xv[r][0] = *(const float4*)&xr[r * HH + 4 * lane];
                xv[r][1] = *(const float4*)&xr[r * HH + 4 * lane + 256];
                xv[r][2] = *(const float4*)&xr[r * HH + 4 * lane + 512];
            }

            float s[2][3];
            #pragma unroll
            for (int r = 0; r < 2; r++)
                #pragma unroll
                for (int j = 0; j < 3; j++) {
                    float a = dot4(xv[r][0], qr[j][0]) + dot4(xv[r][1], qr[j][1])
                            + dot4(xv[r][2], qr[j][2]);
                    s[r][j] = sum64_u(a) + cr[j];
                }

            // online softmax + pool; rescale only when the max grows (uniform branch)
            #pragma unroll
            for (int j = 0; j < 3; j++) {
                float tm = fmaxf(s[0][j], s[1][j]);
                if (tm > m[j]) {
                    float f = __expf(m[j] - tm);
                    m[j] = tm;
                    l[j] *= f;
                    #pragma unroll
                    for (int cc = 0; cc < 12; cc++) P[j][cc] *= f;
                }
                float w0 = __expf(s[0][j] - m[j]);
                float w1 = __expf(s[1][j] - m[j]);
                l[j] += w0 + w1;
                #pragma unroll
                for (int k = 0; k < 3; k++) {
                    P[j][4*k+0] += w0 * xv[0][k].x + w1 * xv[1][k].x;
                    P[j][4*k+1] += w0 * xv[0][k].y + w1 * xv[1][k].y;
                    P[j][4*k+2] += w0 * xv[0][k].z + w1 * xv[1][k].z;
                    P[j][4*k+3] += w0 * xv[0][k].w + w1 * xv[1][k].w;
                }
            }
        }

        __syncthreads();   // staged tile landed; cur free for next stage
    }

    // write partials: head 3w+j, cols 4*lane + 256*k (+0..3)
    size_t blkc = (size_t)b * CPB + cblk;
    #pragma unroll
    for (int j = 0; j < 3; j++) {
        #pragma unroll
        for (int k = 0; k < 3; k++) {
            float4 v = make_float4(P[j][4*k+0], P[j][4*k+1], P[j][4*k+2], P[j][4*k+3]);
            *(float4*)&part[(blkc * NH + 3 * wave + j) * HH + 256 * k + 4 * lane] = v;
        }
        if (lane == 0) {
            pm[blkc * NH + 3 * wave + j] = m[j];
            pl[blkc * NH + 3 * wave + j] = l[j];
        }
    }
}

// ---------------- K2: fused combine + V-proj per head ----------------
// block (h, b): combine 48 chunk partials for head h -> pooled in LDS,
// then op[hd] = w_kv[768+hd] . pooled + b_kv[768+hd] for hd in [64h, 64h+64).
__global__ __launch_bounds__(256) void k_cv(const float* __restrict__ part,
                                            const float* __restrict__ pm,
                                            const float* __restrict__ pl,
                                            const float* __restrict__ w_kv,
                                            const float* __restrict__ b_kv,
                                            float* __restrict__ op) {
    int h = blockIdx.x, b = blockIdx.y, t = threadIdx.x;
    __shared__ float fac[64];
    __shared__ float Ish;
    __shared__ __align__(16) float pv[HH];
    float mval = -1e30f, lval = 0.f;
    if (t < CPB) {
        mval = pm[((size_t)b * CPB + t) * NH + h];
        lval = pl[((size_t)b * CPB + t) * NH + h];
    }
    if (t < 64) {
        float m = mval;
        #pragma unroll
        for (int off = 1; off < 64; off <<= 1) m = fmaxf(m, __shfl_xor(m, off, 64));
        float fc = (t < CPB) ? __expf(mval - m) : 0.f;
        fac[t] = fc;
        float l = lval * fc;
        #pragma unroll
        for (int off = 1; off < 64; off <<= 1) l += __shfl_xor(l, off, 64);
        if (t == 0) Ish = 1.0f / l;
    }
    __syncthreads();
    float inv = Ish;
    #pragma unroll
    for (int kk = 0; kk < 3; kk++) {
        int col = kk * 256 + t;
        float s = 0.f;
        #pragma unroll 8
        for (int c = 0; c < CPB; c++)
            s += part[(((size_t)b * CPB + c) * NH + h) * HH + col] * fac[c];
        pv[col] = s * inv;
    }
    __syncthreads();

    // V-proj: 64 outputs for this head; 4 waves x 16 outputs, wave-dot
    int wave = t >> 6, lane = t & 63;
    #pragma unroll
    for (int o = 0; o < 16; o++) {
        int hd = h * 64 + wave * 16 + o;
        const float* wr = w_kv + (size_t)(HH + hd) * HH + lane * 4;
        float s = 0.f;
        #pragma unroll
        for (int kk = 0; kk < 3; kk++) {
            float4 wv = *(const float4*)(wr + 256 * kk);
            float4 qv = *(const float4*)&pv[lane * 4 + 256 * kk];
            s += dot4(wv, qv);
        }
        #pragma unroll
        for (int off = 1; off < 64; off <<= 1) s += __shfl_xor(s, off, 64);
        if (lane == 0) op[(size_t)b * HH + hd] = s + b_kv[HH + hd];
    }
}

// ---------------- K3: out = gate * (W_out op + b_out)  (grid 24 x BB) ----------------
__global__ __launch_bounds__(256) void k_fin(const float* __restrict__ op_in,
                                             const float* __restrict__ w_out,
                                             const float* __restrict__ b_out,
                                             const float* __restrict__ gate,
                                             float* __restrict__ out) {
    int seg = blockIdx.x, b = blockIdx.y, t = threadIdx.x;
    __shared__ __align__(16) float ov[HH];
    for (int i = t; i < HH; i += 256) ov[i] = op_in[(size_t)b * HH + i];
    __syncthreads();
    int wave = t >> 6, lane = t & 63;
    #pragma unroll
    for (int o = 0; o < 8; o++) {
        int i = seg * 32 + wave * 8 + o;
        const float* wr = w_out + (size_t)i * HH + lane * 4;
        float s = 0.f;
        #pragma unroll
        for (int kk = 0; kk < 3; kk++) {
            float4 wv = *(const float4*)(wr + 256 * kk);
            float4 qv = *(const float4*)&ov[lane * 4 + 256 * kk];
            s += dot4(wv, qv);
        }
        #pragma unroll
        for (int off = 1; off < 64; off <<= 1) s += __shfl_xor(s, off, 64);
        if (lane == 0) out[(size_t)b * HH + i] = gate[i] * (s + b_out[i]);
    }
}

extern "C" void kernel_launch(void* const* d_in, const int* in_sizes, int n_in,
                              void* d_out, int out_size, void* d_ws, size_t ws_size,
                              hipStream_t stream) {
    const float* x      = (const float*)d_in[0];
    const float* query  = (const float*)d_in[1];
    const float* w_kv   = (const float*)d_in[2];
    const float* b_kv   = (const float*)d_in[3];
    const float* w_out  = (const float*)d_in[4];
    const float* b_out  = (const float*)d_in[5];
    const float* w_gate = (const float*)d_in[6];
    const float* b_gate = (const float*)d_in[7];
    float* ws  = (float*)d_ws;
    float* out = (float*)d_out;

    float* gate   = ws + WS_GATE;
    float* opbuf  = ws + WS_OP;
    float* pm     = ws + WS_STATS;
    float* pl     = pm + (size_t)BB * CPB * NH;
    float* part   = pl + (size_t)BB * CPB * NH;

    k_pre<<<133, 256, 0, stream>>>(query, w_kv, b_kv, w_gate, b_gate, ws);
    k_fused<<<dim3(CPB, BB), 256, 0, stream>>>(x, ws, part, pm, pl);
    k_cv<<<dim3(NH, BB), 256, 0, stream>>>(part, pm, pl, w_kv, b_kv, opbuf);
    k_fin<<<dim3(24, BB), 256, 0, stream>>>(opbuf, w_out, b_out, gate, out);
}